// Round 13
// baseline (1301.886 us; speedup 1.0000x reference)
//
#include <hip/hip_runtime.h>
#include <hip/hip_fp8.h>

#define M_DIM 16384
#define N_DIM 4096
#define K_DIM 2048
#define NT64  (K_DIM / 64)     // 32 K-tiles of 64
#define NSB   (K_DIM / 64)     // k-sub-blocks per 32-row block (32 rows x 64 k each)

typedef float floatx16 __attribute__((ext_vector_type(16)));
typedef int   intx4    __attribute__((ext_vector_type(4)));
typedef int   intx8    __attribute__((ext_vector_type(8)));

__device__ __forceinline__ unsigned char f32_to_fp8(float v) {
    __hip_fp8_e4m3 t(v);
    return t.__x;
}

__device__ __forceinline__ float fp8_roundtrip(float v) {
    __hip_fp8_e4m3 t(v);
    return (float)t;
}

// async global->LDS, 16B per lane. LDS dest is wave-uniform base + lane*16.
__device__ __forceinline__ void async16(const void* g, void* l) {
    __builtin_amdgcn_global_load_lds((__attribute__((address_space(1))) void*)g,
                                     (__attribute__((address_space(3))) void*)l,
                                     16, 0, 0);
}

// read a lane-linear 32B fragment: two 16B halves 1024B apart (zero-conflict)
__device__ __forceinline__ intx8 ld8(const unsigned char* p) {
    intx4 lo = *(const intx4*)(p);
    intx4 hi = *(const intx4*)(p + 1024);
    return __builtin_shufflevector(lo, hi, 0, 1, 2, 3, 4, 5, 6, 7);
}

// ---- quantize + pack into 32x32x64-MFMA fragment order (unchanged) ----
// Sub-block = 32 rows x 64 k = 2048 B. qX[rb][kt][2048], rb = m>>5, kt = k>>6.
// Lane l (r = l&31, h = l>>5) owns k-window kt*64 + h*32 .. +31, stored as
// bytes 0-15 at l*16 and bytes 16-31 at 1024 + l*16. Staging is identity
// (lane-linear 16B), fragment reads are lane-linear ds_read_b128 -> zero bank
// conflicts. A and B share this map, so any hardware-internal k permutation
// cancels in the MFMA dot product.
__global__ void quant_pack_kernel(const float* __restrict__ in,
                                  unsigned char* __restrict__ out,
                                  const float* __restrict__ sp) {
    const int p = blockIdx.x * blockDim.x + threadIdx.x;  // one 16B packed chunk
    const float s = sp ? *sp : 1.0f;
    const int c    = p & 127;            // chunk within sub-block
    const int sb   = p >> 7;
    const int kt   = sb & (NSB - 1);
    const int rb   = sb >> 5;            // log2(NSB) = 5
    const int half = c >> 6;
    const int l    = c & 63;
    const size_t m = (size_t)rb * 32 + (l & 31);
    const int   k0 = kt * 64 + (l >> 5) * 32 + half * 16;
    const float* src = in + m * K_DIM + k0;
    float f[16];
    *(float4*)(f)      = *(const float4*)(src);
    *(float4*)(f + 4)  = *(const float4*)(src + 4);
    *(float4*)(f + 8)  = *(const float4*)(src + 8);
    *(float4*)(f + 12) = *(const float4*)(src + 12);
    unsigned long long lo = 0, hi = 0;
#pragma unroll
    for (int j = 0; j < 8; ++j) {
        float v0 = fminf(fmaxf(f[j] * s, -0.5f), 0.5f);
        float v1 = fminf(fmaxf(f[j + 8] * s, -0.5f), 0.5f);
        lo |= (unsigned long long)f32_to_fp8(v0) << (8 * j);
        hi |= (unsigned long long)f32_to_fp8(v1) << (8 * j);
    }
    unsigned long long* dst = (unsigned long long*)(out + (size_t)p * 16);
    dst[0] = lo;
    dst[1] = hi;
}

#define MF(A_, B_, C_) (C_) = __builtin_amdgcn_mfma_scale_f32_32x32x64_f8f6f4( \
        (A_), (B_), (C_), 0, 0, 0, 0x7F7F7F7F, 0, 0x7F7F7F7F)

// ---- MX-fp8 GEMM: 256x256 tile, BK=64, PRODUCER-CONSUMER wave split ----
// 9 waves: waves 0-7 = consumers (2Mx4N, 128x64 output sub-tile each, pure
// LDS+MFMA stream, NO vmem instructions); wave 8 = producer (all staging,
// 4-stage ring staged 2 tiles ahead, counted vmcnt(32) never drained to 0).
// Cross-wave RAW: producer's vmcnt(32)-then-s_barrier at tile k proves stage k
// landed chip-side before any consumer reads it. WAR: producer issues stage
// k+2 (buffer (k+2)&3 = (k-2)&3) only after barrier k; consumers' tile k-2
// ds_reads retired before their tile k-2 MFMAs, hence before barrier k-1.
// Scales fixed at e8m0 1.0 (0x7F) -> numerically identical to plain fp8 GEMM.
__global__ __launch_bounds__(576, 1) void gemm_fp8_kernel(
        const unsigned char* __restrict__ qA, const unsigned char* __restrict__ qB,
        const float* __restrict__ bias, float* __restrict__ out) {
    __shared__ unsigned char Al[4][8 * 2048];   // 4 stages x 16 KB (256 rows x 64 k)
    __shared__ unsigned char Bl[4][8 * 2048];   // 4 stages x 16 KB

    const int tid  = threadIdx.x;
    const int lane = tid & 63;
    const int wid  = tid >> 6;           // 0..8

    // XCD-aware swizzle: 1024 blocks % 8 == 0 -> bijective simple form
    const int cpx = gridDim.x >> 3;
    const int swz = (blockIdx.x & 7) * cpx + (blockIdx.x >> 3);
    const int bm = swz & 63;             // M/256 = 64 tiles
    const int bn = swz >> 6;             // N/256 = 16 tiles

    if (wid == 8) {
        // ================= PRODUCER =================
        // row-block stride = NSB*2048 = 64 KB; per-tile offset = t*2048.
        const unsigned char* gA = qA + ((size_t)(bm * 8) << 16) + (lane << 4);
        const unsigned char* gB = qB + ((size_t)(bn * 8) << 16) + (lane << 4);
#define PSTAGE(S_, T_) do {                                                  \
        const size_t go_ = (size_t)(T_) * 2048;                              \
        _Pragma("unroll")                                                    \
        for (int sb = 0; sb < 8; ++sb) {                                     \
            async16(gA + ((size_t)sb << 16) + go_,        &Al[S_][sb * 2048]);        \
            async16(gA + ((size_t)sb << 16) + go_ + 1024, &Al[S_][sb * 2048 + 1024]); \
            async16(gB + ((size_t)sb << 16) + go_,        &Bl[S_][sb * 2048]);        \
            async16(gB + ((size_t)sb << 16) + go_ + 1024, &Bl[S_][sb * 2048 + 1024]); \
        }                                                                    \
    } while (0)
        PSTAGE(0, 0);
        PSTAGE(1, 1);
        for (int k = 0; k < NT64; ++k) {
            if (k < NT64 - 1) asm volatile("s_waitcnt vmcnt(32)" ::: "memory");
            else              asm volatile("s_waitcnt vmcnt(0)" ::: "memory");
            __builtin_amdgcn_s_barrier();
            if (k + 2 < NT64) PSTAGE((k + 2) & 3, k + 2);
        }
        return;   // no epilogue; consumers have no further barriers
    }

    // ================= CONSUMERS =================
    // wave (g = wid>>2, cc = wid&3) owns a 128x64 output sub-tile
    const int g  = wid >> 2;
    const int cc = wid & 3;

    floatx16 acc[4][2] = {};             // 4 row-blocks x 2 col-blocks of 32x32

    for (int k = 0; k < NT64; ++k) {
        __builtin_amdgcn_s_barrier();    // stage k published by producer
        const int s = k & 3;
        intx8 a0 = ld8(&Al[s][(4 * g + 0) * 2048 + (lane << 4)]);
        intx8 a1 = ld8(&Al[s][(4 * g + 1) * 2048 + (lane << 4)]);
        intx8 a2 = ld8(&Al[s][(4 * g + 2) * 2048 + (lane << 4)]);
        intx8 a3 = ld8(&Al[s][(4 * g + 3) * 2048 + (lane << 4)]);
        intx8 b0 = ld8(&Bl[s][(2 * cc + 0) * 2048 + (lane << 4)]);
        intx8 b1 = ld8(&Bl[s][(2 * cc + 1) * 2048 + (lane << 4)]);
        __builtin_amdgcn_s_setprio(1);
        MF(a0, b0, acc[0][0]); MF(a0, b1, acc[0][1]);
        MF(a1, b0, acc[1][0]); MF(a1, b1, acc[1][1]);
        MF(a2, b0, acc[2][0]); MF(a2, b1, acc[2][1]);
        MF(a3, b0, acc[3][0]); MF(a3, b1, acc[3][1]);
        __builtin_amdgcn_s_setprio(0);
    }

    // epilogue: 32x32 C/D layout col=lane&31, row=(r&3)+8*(r>>2)+4*(lane>>5)
    const int orow_b = bm * 256 + g * 128 + ((lane >> 5) << 2);
    const int ocol_b = bn * 256 + cc * 64 + (lane & 31);
#pragma unroll
    for (int ni = 0; ni < 2; ++ni) {
        const int oc = ocol_b + ni * 32;
        const float bv = bias[oc];
#pragma unroll
        for (int mi = 0; mi < 4; ++mi) {
#pragma unroll
            for (int r = 0; r < 16; ++r) {
                const int orow = orow_b + mi * 32 + (r & 3) + 8 * (r >> 2);
                out[(size_t)orow * N_DIM + oc] = fp8_roundtrip(acc[mi][ni][r]) + bv;
            }
        }
    }
}

// ---- fallback (only if ws too small): 1 thread per output, exact fp32 accumulation ----
__global__ void naive_kernel(const float* __restrict__ x, const float* __restrict__ w,
                             const float* __restrict__ bias, const float* __restrict__ sp,
                             float* __restrict__ out) {
    const int ncol = blockIdx.x * blockDim.x + threadIdx.x;
    const int m = blockIdx.y;
    const float s = *sp;
    float acc = 0.f;
    for (int k = 0; k < K_DIM; ++k) {
        float q = fp8_roundtrip(fminf(fmaxf(x[(size_t)m * K_DIM + k] * s, -0.5f), 0.5f));
        acc += q * w[(size_t)ncol * K_DIM + k];
    }
    out[(size_t)m * N_DIM + ncol] = fp8_roundtrip(acc) + bias[ncol];
}

extern "C" void kernel_launch(void* const* d_in, const int* in_sizes, int n_in,
                              void* d_out, int out_size, void* d_ws, size_t ws_size,
                              hipStream_t stream) {
    const float* x     = (const float*)d_in[0];
    const float* w     = (const float*)d_in[1];
    const float* bias  = (const float*)d_in[2];
    const float* scale = (const float*)d_in[3];
    float* out = (float*)d_out;

    const size_t needA = (size_t)M_DIM * K_DIM;   // 33.5 MB fp8
    const size_t needB = (size_t)N_DIM * K_DIM;   //  8.4 MB fp8

    if (ws_size >= needA + needB) {
        unsigned char* qA = (unsigned char*)d_ws;
        unsigned char* qB = qA + needA;
        quant_pack_kernel<<<(M_DIM * K_DIM / 16) / 256, 256, 0, stream>>>(x, qA, scale);
        quant_pack_kernel<<<(N_DIM * K_DIM / 16) / 256, 256, 0, stream>>>(w, qB, nullptr);
        gemm_fp8_kernel<<<(M_DIM / 256) * (N_DIM / 256), 576, 0, stream>>>(qA, qB, bias, out);
    } else {
        dim3 g(N_DIM / 256, M_DIM);
        naive_kernel<<<g, 256, 0, stream>>>(x, w, bias, scale, out);
    }
}

// Round 14
// 255.038 us; speedup vs baseline: 5.1047x; 5.1047x over previous
//
#include <hip/hip_runtime.h>
#include <hip/hip_fp8.h>

#define M_DIM 16384
#define N_DIM 4096
#define K_DIM 2048
#define NT64  (K_DIM / 64)     // 32 K-tiles of 64
#define NSB   (K_DIM / 64)     // k-sub-blocks per 32-row block (32 rows x 64 k each)

typedef float floatx16 __attribute__((ext_vector_type(16)));
typedef int   intx4    __attribute__((ext_vector_type(4)));
typedef int   intx8    __attribute__((ext_vector_type(8)));

__device__ __forceinline__ unsigned char f32_to_fp8(float v) {
    __hip_fp8_e4m3 t(v);
    return t.__x;
}

__device__ __forceinline__ float fp8_roundtrip(float v) {
    __hip_fp8_e4m3 t(v);
    return (float)t;
}

// async global->LDS, 16B per lane. LDS dest is wave-uniform base + lane*16.
__device__ __forceinline__ void async16(const void* g, void* l) {
    __builtin_amdgcn_global_load_lds((__attribute__((address_space(1))) void*)g,
                                     (__attribute__((address_space(3))) void*)l,
                                     16, 0, 0);
}

// read a lane-linear 32B fragment: two 16B halves 1024B apart (zero-conflict)
__device__ __forceinline__ intx8 ld8(const unsigned char* p) {
    intx4 lo = *(const intx4*)(p);
    intx4 hi = *(const intx4*)(p + 1024);
    return __builtin_shufflevector(lo, hi, 0, 1, 2, 3, 4, 5, 6, 7);
}

// ---- quantize + pack into 32x32x64-MFMA fragment order (unchanged) ----
// Sub-block = 32 rows x 64 k = 2048 B. qX[rb][kt][2048], rb = m>>5, kt = k>>6.
// Lane l (r = l&31, h = l>>5) owns k-window kt*64 + h*32 .. +31, stored as
// bytes 0-15 at l*16 and bytes 16-31 at 1024 + l*16. Staging is identity
// (lane-linear 16B), fragment reads are lane-linear ds_read_b128 -> zero bank
// conflicts. A and B share this map, so any hardware-internal k permutation
// cancels in the MFMA dot product.
__global__ void quant_pack_kernel(const float* __restrict__ in,
                                  unsigned char* __restrict__ out,
                                  const float* __restrict__ sp) {
    const int p = blockIdx.x * blockDim.x + threadIdx.x;  // one 16B packed chunk
    const float s = sp ? *sp : 1.0f;
    const int c    = p & 127;            // chunk within sub-block
    const int sb   = p >> 7;
    const int kt   = sb & (NSB - 1);
    const int rb   = sb >> 5;            // log2(NSB) = 5
    const int half = c >> 6;
    const int l    = c & 63;
    const size_t m = (size_t)rb * 32 + (l & 31);
    const int   k0 = kt * 64 + (l >> 5) * 32 + half * 16;
    const float* src = in + m * K_DIM + k0;
    float f[16];
    *(float4*)(f)      = *(const float4*)(src);
    *(float4*)(f + 4)  = *(const float4*)(src + 4);
    *(float4*)(f + 8)  = *(const float4*)(src + 8);
    *(float4*)(f + 12) = *(const float4*)(src + 12);
    unsigned long long lo = 0, hi = 0;
#pragma unroll
    for (int j = 0; j < 8; ++j) {
        float v0 = fminf(fmaxf(f[j] * s, -0.5f), 0.5f);
        float v1 = fminf(fmaxf(f[j + 8] * s, -0.5f), 0.5f);
        lo |= (unsigned long long)f32_to_fp8(v0) << (8 * j);
        hi |= (unsigned long long)f32_to_fp8(v1) << (8 * j);
    }
    unsigned long long* dst = (unsigned long long*)(out + (size_t)p * 16);
    dst[0] = lo;
    dst[1] = hi;
}

#define MF(A_, B_, C_) (C_) = __builtin_amdgcn_mfma_scale_f32_32x32x64_f8f6f4( \
        (A_), (B_), (C_), 0, 0, 0, 0x7F7F7F7F, 0, 0x7F7F7F7F)

// ---- MX-fp8 GEMM: 128x128 tile, BK=64, PRODUCER-CONSUMER, 2 blocks/CU ----
// 5 waves: waves 0-3 = consumers (2x2 of 64x64, pure {barrier; 4 ld8; 4 MFMA}
// stream, NO vmem instructions); wave 4 = producer (all staging, 4-stage ring
// staged 2 ahead, counted vmcnt(16), drained only at the tail).
// Spill-proof: consumer needs ~115 VGPR < 168 cap at 3 waves/SIMD; 64 KB LDS
// -> 2 independent blocks/CU add cross-block slip (m114) on top of role split.
// RAW: producer's vmcnt(16)-then-s_barrier at tile k proves stage k landed.
// WAR: stage k+2 (issued after barrier k) overwrites buffer (k-2)&3, whose
// consumer reads retired (lgkm-waited by their MFMAs) before barrier k-1.
// Scales fixed at e8m0 1.0 (0x7F) -> numerically identical to plain fp8 GEMM.
__global__ __launch_bounds__(320, 3) void gemm_fp8_kernel(
        const unsigned char* __restrict__ qA, const unsigned char* __restrict__ qB,
        const float* __restrict__ bias, float* __restrict__ out) {
    __shared__ unsigned char Al[4][4 * 2048];   // 4 stages x 8 KB (128 rows x 64 k)
    __shared__ unsigned char Bl[4][4 * 2048];   // 4 stages x 8 KB

    const int tid  = threadIdx.x;
    const int lane = tid & 63;
    const int wid  = tid >> 6;           // 0..4

    // XCD-aware swizzle: 4096 blocks % 8 == 0 -> bijective simple form
    const int cpx = gridDim.x >> 3;
    const int swz = (blockIdx.x & 7) * cpx + (blockIdx.x >> 3);
    const int bm = swz & 127;            // M/128 = 128 tiles
    const int bn = swz >> 7;             // N/128 = 32 tiles

    if (wid == 4) {
        // ================= PRODUCER =================
        // row-block stride = NSB*2048 = 64 KB; per-tile offset = t*2048.
        const unsigned char* gA = qA + ((size_t)(bm * 4) << 16) + (lane << 4);
        const unsigned char* gB = qB + ((size_t)(bn * 4) << 16) + (lane << 4);
#define PSTAGE(S_, T_) do {                                                  \
        const size_t go_ = (size_t)(T_) * 2048;                              \
        _Pragma("unroll")                                                    \
        for (int sb = 0; sb < 4; ++sb) {                                     \
            async16(gA + ((size_t)sb << 16) + go_,        &Al[S_][sb * 2048]);        \
            async16(gA + ((size_t)sb << 16) + go_ + 1024, &Al[S_][sb * 2048 + 1024]); \
            async16(gB + ((size_t)sb << 16) + go_,        &Bl[S_][sb * 2048]);        \
            async16(gB + ((size_t)sb << 16) + go_ + 1024, &Bl[S_][sb * 2048 + 1024]); \
        }                                                                    \
    } while (0)
        PSTAGE(0, 0);
        PSTAGE(1, 1);
        for (int k = 0; k < NT64; ++k) {
            if (k < NT64 - 1) asm volatile("s_waitcnt vmcnt(16)" ::: "memory");
            else              asm volatile("s_waitcnt vmcnt(0)" ::: "memory");
            __builtin_amdgcn_s_barrier();
            if (k + 2 < NT64) PSTAGE((k + 2) & 3, k + 2);
        }
        return;   // consumers have no further barriers
    }

    // ================= CONSUMERS =================
    // wave (g = wid>>1, cc = wid&1) owns a 64x64 output sub-tile
    const int g  = wid >> 1;
    const int cc = wid & 1;

    floatx16 acc[2][2] = {};             // 2x2 of 32x32 = 64 VGPR

    for (int k = 0; k < NT64; ++k) {
        __builtin_amdgcn_s_barrier();    // stage k published by producer
        const int s = k & 3;
        intx8 a0 = ld8(&Al[s][(2 * g + 0) * 2048 + (lane << 4)]);
        intx8 a1 = ld8(&Al[s][(2 * g + 1) * 2048 + (lane << 4)]);
        intx8 b0 = ld8(&Bl[s][(2 * cc + 0) * 2048 + (lane << 4)]);
        intx8 b1 = ld8(&Bl[s][(2 * cc + 1) * 2048 + (lane << 4)]);
        __builtin_amdgcn_s_setprio(1);
        MF(a0, b0, acc[0][0]); MF(a0, b1, acc[0][1]);
        MF(a1, b0, acc[1][0]); MF(a1, b1, acc[1][1]);
        __builtin_amdgcn_s_setprio(0);
    }

    // epilogue: 32x32 C/D layout col=lane&31, row=(r&3)+8*(r>>2)+4*(lane>>5)
    const int orow_b = bm * 128 + g * 64 + ((lane >> 5) << 2);
    const int ocol_b = bn * 128 + cc * 64 + (lane & 31);
#pragma unroll
    for (int ni = 0; ni < 2; ++ni) {
        const int oc = ocol_b + ni * 32;
        const float bv = bias[oc];
#pragma unroll
        for (int mi = 0; mi < 2; ++mi) {
#pragma unroll
            for (int r = 0; r < 16; ++r) {
                const int orow = orow_b + mi * 32 + (r & 3) + 8 * (r >> 2);
                out[(size_t)orow * N_DIM + oc] = fp8_roundtrip(acc[mi][ni][r]) + bv;
            }
        }
    }
}

// ---- fallback (only if ws too small): 1 thread per output, exact fp32 accumulation ----
__global__ void naive_kernel(const float* __restrict__ x, const float* __restrict__ w,
                             const float* __restrict__ bias, const float* __restrict__ sp,
                             float* __restrict__ out) {
    const int ncol = blockIdx.x * blockDim.x + threadIdx.x;
    const int m = blockIdx.y;
    const float s = *sp;
    float acc = 0.f;
    for (int k = 0; k < K_DIM; ++k) {
        float q = fp8_roundtrip(fminf(fmaxf(x[(size_t)m * K_DIM + k] * s, -0.5f), 0.5f));
        acc += q * w[(size_t)ncol * K_DIM + k];
    }
    out[(size_t)m * N_DIM + ncol] = fp8_roundtrip(acc) + bias[ncol];
}

extern "C" void kernel_launch(void* const* d_in, const int* in_sizes, int n_in,
                              void* d_out, int out_size, void* d_ws, size_t ws_size,
                              hipStream_t stream) {
    const float* x     = (const float*)d_in[0];
    const float* w     = (const float*)d_in[1];
    const float* bias  = (const float*)d_in[2];
    const float* scale = (const float*)d_in[3];
    float* out = (float*)d_out;

    const size_t needA = (size_t)M_DIM * K_DIM;   // 33.5 MB fp8
    const size_t needB = (size_t)N_DIM * K_DIM;   //  8.4 MB fp8

    if (ws_size >= needA + needB) {
        unsigned char* qA = (unsigned char*)d_ws;
        unsigned char* qB = qA + needA;
        quant_pack_kernel<<<(M_DIM * K_DIM / 16) / 256, 256, 0, stream>>>(x, qA, scale);
        quant_pack_kernel<<<(N_DIM * K_DIM / 16) / 256, 256, 0, stream>>>(w, qB, nullptr);
        gemm_fp8_kernel<<<(M_DIM / 128) * (N_DIM / 128), 320, 0, stream>>>(qA, qB, bias, out);
    } else {
        dim3 g(N_DIM / 256, M_DIM);
        naive_kernel<<<g, 256, 0, stream>>>(x, w, bias, scale, out);
    }
}

// Round 15
// 205.777 us; speedup vs baseline: 6.3267x; 1.2394x over previous
//
#include <hip/hip_runtime.h>
#include <hip/hip_fp8.h>

#define M_DIM 16384
#define N_DIM 4096
#define K_DIM 2048
#define NT64  (K_DIM / 64)     // 32 K-tiles of 64
#define NSB   (K_DIM / 64)     // k-sub-blocks per 32-row block (32 rows x 64 k each)
#define NXCHUNK (M_DIM * K_DIM / 16)   // x packed chunks (8192 blocks of 256)

typedef float floatx16 __attribute__((ext_vector_type(16)));
typedef int   intx4    __attribute__((ext_vector_type(4)));
typedef int   intx8    __attribute__((ext_vector_type(8)));

__device__ __forceinline__ unsigned char f32_to_fp8(float v) {
    __hip_fp8_e4m3 t(v);
    return t.__x;
}

__device__ __forceinline__ float fp8_roundtrip(float v) {
    __hip_fp8_e4m3 t(v);
    return (float)t;
}

// async global->LDS, 16B per lane. LDS dest is wave-uniform base + lane*16.
__device__ __forceinline__ void async16(const void* g, void* l) {
    __builtin_amdgcn_global_load_lds((__attribute__((address_space(1))) void*)g,
                                     (__attribute__((address_space(3))) void*)l,
                                     16, 0, 0);
}

// read a lane-linear 32B fragment: two 16B halves 1024B apart (zero-conflict)
__device__ __forceinline__ intx8 ld8(const unsigned char* p) {
    intx4 lo = *(const intx4*)(p);
    intx4 hi = *(const intx4*)(p + 1024);
    return __builtin_shufflevector(lo, hi, 0, 1, 2, 3, 4, 5, 6, 7);
}

// ---- fused quantize+pack for BOTH x and w (one launch, block-uniform split) ----
// Packing (per 32-row x 64-k sub-block of 2048 B): qX[rb][kt][2048], rb=m>>5,
// kt=k>>6. Lane l (r=l&31, h=l>>5) owns k-window kt*64+h*32..+31, stored as
// bytes 0-15 at l*16 and bytes 16-31 at 1024+l*16. GEMM staging is identity
// (lane-linear 16B) and fragment reads are lane-linear ds_read_b128 -> zero
// bank conflicts. A and B share this map, so any hardware-internal k
// permutation cancels in the MFMA dot product.
__global__ void quant_pack_kernel(const float* __restrict__ xin,
                                  const float* __restrict__ win,
                                  unsigned char* __restrict__ qA,
                                  unsigned char* __restrict__ qB,
                                  const float* __restrict__ sp) {
    int p = blockIdx.x * blockDim.x + threadIdx.x;   // one 16B packed chunk
    const float* in;
    unsigned char* out;
    float s;
    if (p < NXCHUNK) {               // x-range: 8192 full blocks, no divergence
        in = xin; out = qA; s = *sp;
    } else {                         // w-range: 2048 full blocks
        p -= NXCHUNK; in = win; out = qB; s = 1.0f;
    }
    const int c    = p & 127;            // chunk within sub-block
    const int sb   = p >> 7;
    const int kt   = sb & (NSB - 1);
    const int rb   = sb >> 5;            // log2(NSB) = 5
    const int half = c >> 6;
    const int l    = c & 63;
    const size_t m = (size_t)rb * 32 + (l & 31);
    const int   k0 = kt * 64 + (l >> 5) * 32 + half * 16;
    const float* src = in + m * K_DIM + k0;
    float f[16];
    *(float4*)(f)      = *(const float4*)(src);
    *(float4*)(f + 4)  = *(const float4*)(src + 4);
    *(float4*)(f + 8)  = *(const float4*)(src + 8);
    *(float4*)(f + 12) = *(const float4*)(src + 12);
    unsigned long long lo = 0, hi = 0;
#pragma unroll
    for (int j = 0; j < 8; ++j) {
        float v0 = fminf(fmaxf(f[j] * s, -0.5f), 0.5f);
        float v1 = fminf(fmaxf(f[j + 8] * s, -0.5f), 0.5f);
        lo |= (unsigned long long)f32_to_fp8(v0) << (8 * j);
        hi |= (unsigned long long)f32_to_fp8(v1) << (8 * j);
    }
    unsigned long long* dst = (unsigned long long*)(out + (size_t)p * 16);
    dst[0] = lo;
    dst[1] = hi;
}

// stage one BK=64 tile slice (wave wid's 32-row A block + 32-col B block)
#define STAGE(s_, t_) do {                                                  \
    const size_t go_ = (size_t)(t_) * 2048;                                 \
    async16(gAw + go_,        &Al[(s_)][wid * 2048]);                       \
    async16(gAw + go_ + 1024, &Al[(s_)][wid * 2048 + 1024]);                \
    async16(gBw + go_,        &Bl[(s_)][wid * 2048]);                       \
    async16(gBw + go_ + 1024, &Bl[(s_)][wid * 2048 + 1024]);                \
} while (0)

// one K=64 tile: counted vmcnt (never 0 in steady state), ONE raw barrier,
// lane-linear ds_reads, stage t+3, setprio'd MFMA cluster.
#define TILE(t_, VM_, ST_) do {                                             \
    asm volatile("s_waitcnt vmcnt(" VM_ ")" ::: "memory");                  \
    __builtin_amdgcn_s_barrier();                                           \
    const int s_ = (t_) & 3;                                                \
    intx8 a_[4], b_[2];                                                     \
    _Pragma("unroll")                                                       \
    for (int mi = 0; mi < 4; ++mi)                                          \
        a_[mi] = ld8(&Al[s_][(4 * g + mi) * 2048 + (lane << 4)]);           \
    _Pragma("unroll")                                                       \
    for (int ni = 0; ni < 2; ++ni)                                          \
        b_[ni] = ld8(&Bl[s_][(2 * cc + ni) * 2048 + (lane << 4)]);          \
    if (ST_) STAGE(((t_) + 3) & 3, (t_) + 3);                               \
    __builtin_amdgcn_s_setprio(1);                                          \
    _Pragma("unroll")                                                       \
    for (int mi = 0; mi < 4; ++mi)                                          \
        _Pragma("unroll")                                                   \
        for (int ni = 0; ni < 2; ++ni)                                      \
            acc[mi][ni] = __builtin_amdgcn_mfma_scale_f32_32x32x64_f8f6f4(  \
                a_[mi], b_[ni], acc[mi][ni], 0, 0, 0, 0x7F7F7F7F, 0, 0x7F7F7F7F); \
    __builtin_amdgcn_s_setprio(0);                                          \
} while (0)

// ---- MX-fp8 GEMM: 256x256 tile, BK=64, 8 waves (2Mx4N), 32x32x64 scaled MFMA ----
// Best-measured structure (R8): 4-deep LDS stage ring staged 3 ahead; per tile
// ONE counted vmcnt + ONE raw s_barrier (no full drain in the main loop).
// Ring correctness: RAW -- wave's vmcnt(8) before the barrier proves its own
// stage-t landed; barrier collects all waves. WAR -- stage t+3 overwrites the
// buffer last read at t-1; every wave's t-1 reads completed (lgkm-waited by
// its t-1 MFMAs) before it reached this barrier.
// Scales fixed at e8m0 1.0 (0x7F) -> numerically identical to plain fp8 GEMM.
__global__ __launch_bounds__(512, 1) void gemm_fp8_kernel(
        const unsigned char* __restrict__ qA, const unsigned char* __restrict__ qB,
        const float* __restrict__ bias, float* __restrict__ out) {
    __shared__ unsigned char Al[4][8 * 2048];   // 4 stages x 16 KB (256 rows x 64 k)
    __shared__ unsigned char Bl[4][8 * 2048];   // 4 stages x 16 KB

    const int tid  = threadIdx.x;
    const int lane = tid & 63;
    const int wid  = tid >> 6;           // 0..7

    // XCD-aware swizzle: 1024 blocks % 8 == 0 -> bijective simple form
    const int cpx = gridDim.x >> 3;
    const int swz = (blockIdx.x & 7) * cpx + (blockIdx.x >> 3);
    const int bm = swz & 63;             // M/256 = 64 tiles
    const int bn = swz >> 6;             // N/256 = 16 tiles

    // staging: wave wid owns A row-block (bm*8+wid) / B col-block (bn*8+wid);
    // row-block stride = NSB*2048 = 64 KB; per-tile offset = t*2048.
    const unsigned char* gAw = qA + ((size_t)(bm * 8 + wid) << 16) + (lane << 4);
    const unsigned char* gBw = qB + ((size_t)(bn * 8 + wid) << 16) + (lane << 4);

    // compute: wave (g = wid>>2, cc = wid&3) owns a 128x64 output sub-tile
    const int g  = wid >> 2;
    const int cc = wid & 3;

    floatx16 acc[4][2] = {};             // 4 row-blocks x 2 col-blocks of 32x32

    // ---- prologue: stage tiles 0,1,2 (12 loads/wave outstanding) ----
#pragma unroll
    for (int s = 0; s < 3; ++s) STAGE(s, s);

    // ---- main loop: steady-state vmcnt(8) = stages t+1,t+2 stay in flight ----
    for (int t = 0; t < NT64 - 3; ++t) {
        TILE(t, "8", 1);
    }
    // ---- epilogue peel: ring drains 8 -> 4 -> 0 ----
    TILE(NT64 - 3, "8", 0);
    TILE(NT64 - 2, "4", 0);
    TILE(NT64 - 1, "0", 0);

    // epilogue: 32x32 C/D layout col=lane&31, row=(r&3)+8*(r>>2)+4*(lane>>5)
    const int orow_b = bm * 256 + g * 128 + ((lane >> 5) << 2);
    const int ocol_b = bn * 256 + cc * 64 + (lane & 31);
#pragma unroll
    for (int ni = 0; ni < 2; ++ni) {
        const int oc = ocol_b + ni * 32;
        const float bv = bias[oc];
#pragma unroll
        for (int mi = 0; mi < 4; ++mi) {
#pragma unroll
            for (int r = 0; r < 16; ++r) {
                const int orow = orow_b + mi * 32 + (r & 3) + 8 * (r >> 2);
                out[(size_t)orow * N_DIM + oc] = fp8_roundtrip(acc[mi][ni][r]) + bv;
            }
        }
    }
}

// ---- fallback (only if ws too small): 1 thread per output, exact fp32 accumulation ----
__global__ void naive_kernel(const float* __restrict__ x, const float* __restrict__ w,
                             const float* __restrict__ bias, const float* __restrict__ sp,
                             float* __restrict__ out) {
    const int ncol = blockIdx.x * blockDim.x + threadIdx.x;
    const int m = blockIdx.y;
    const float s = *sp;
    float acc = 0.f;
    for (int k = 0; k < K_DIM; ++k) {
        float q = fp8_roundtrip(fminf(fmaxf(x[(size_t)m * K_DIM + k] * s, -0.5f), 0.5f));
        acc += q * w[(size_t)ncol * K_DIM + k];
    }
    out[(size_t)m * N_DIM + ncol] = fp8_roundtrip(acc) + bias[ncol];
}

extern "C" void kernel_launch(void* const* d_in, const int* in_sizes, int n_in,
                              void* d_out, int out_size, void* d_ws, size_t ws_size,
                              hipStream_t stream) {
    const float* x     = (const float*)d_in[0];
    const float* w     = (const float*)d_in[1];
    const float* bias  = (const float*)d_in[2];
    const float* scale = (const float*)d_in[3];
    float* out = (float*)d_out;

    const size_t needA = (size_t)M_DIM * K_DIM;   // 33.5 MB fp8
    const size_t needB = (size_t)N_DIM * K_DIM;   //  8.4 MB fp8

    if (ws_size >= needA + needB) {
        unsigned char* qA = (unsigned char*)d_ws;
        unsigned char* qB = qA + needA;
        const int nchunks = (M_DIM * K_DIM + N_DIM * K_DIM) / 16;
        quant_pack_kernel<<<nchunks / 256, 256, 0, stream>>>(x, w, qA, qB, scale);
        gemm_fp8_kernel<<<(M_DIM / 256) * (N_DIM / 256), 512, 0, stream>>>(qA, qB, bias, out);
    } else {
        dim3 g(N_DIM / 256, M_DIM);
        naive_kernel<<<g, 256, 0, stream>>>(x, w, bias, scale, out);
    }
}